// Round 1
// baseline (2528.416 us; speedup 1.0000x reference)
//
#include <hip/hip_runtime.h>

// LaplacianKnn: y_{s+1}[i] = a*y_s[i] + b * (sum_j t_j*y_s[n_j]) / (sum_j t_j)
//   t_j = exp(-dist[i][j]/eps) * Dinv[n_j]          (D[i] factor cancels!)
//   a = 4/eps + 2*nu/k^2 + 10,  b = -4/eps
// out = dot(x, y_3)
// z[i] = (y[i], Dinv[i]) packed float2 so the per-edge random gather is one
// 8B transaction instead of two 4B ones into the same cache footprint.

static constexpr int BLOCK = 256;

__global__ __launch_bounds__(256) void dinv_kernel(
    const float* __restrict__ dist,
    const float* __restrict__ x,
    const float* __restrict__ eps_p,
    float2* __restrict__ z0,
    int n_edges) {
  int e = blockIdx.x * BLOCK + threadIdx.x;  // one lane per edge
  float inv_eps = 1.0f / eps_p[0];
  float w = 0.0f;
  if (e < n_edges) w = __expf(-dist[e] * inv_eps);
  // reduce over the 32 lanes of one node's row
  #pragma unroll
  for (int off = 16; off > 0; off >>= 1)
    w += __shfl_down(w, off, 32);
  if ((threadIdx.x & 31) == 0 && e < n_edges) {
    int node = e >> 5;
    z0[node] = make_float2(x[node], 1.0f / w);
  }
}

template <bool LAST>
__global__ __launch_bounds__(256) void sweep_kernel(
    const float* __restrict__ dist,
    const int* __restrict__ nbr,
    const float2* __restrict__ zin,
    float2* __restrict__ zout,
    const float* __restrict__ x,
    const float* __restrict__ eps_p,
    const float* __restrict__ k_p,
    const int* __restrict__ nu_p,
    float* __restrict__ out,
    int n_edges) {
  __shared__ float bsum;
  if (LAST) {
    if (threadIdx.x == 0) bsum = 0.0f;
    __syncthreads();
  }
  int e = blockIdx.x * BLOCK + threadIdx.x;  // one lane per edge
  float inv_eps = 1.0f / eps_p[0];
  float t = 0.0f, g = 0.0f;
  if (e < n_edges) {
    int j = nbr[e];            // coalesced stream
    float2 zn = zin[j];        // random 8B gather (L2/L3-resident, 8 MB array)
    t = __expf(-dist[e] * inv_eps) * zn.y;  // zn.y = Dinv[j]
    g = t * zn.x;                            // zn.x = y[j]
  }
  #pragma unroll
  for (int off = 16; off > 0; off >>= 1) {
    t += __shfl_down(t, off, 32);
    g += __shfl_down(g, off, 32);
  }
  if ((threadIdx.x & 31) == 0 && e < n_edges) {
    int node = e >> 5;
    float2 zc = zin[node];     // own (y, Dinv)
    float kk = k_p[0];
    float a = 4.0f * inv_eps + 2.0f * (float)nu_p[0] / (kk * kk) + 10.0f;
    float b = -4.0f * inv_eps;
    float ynew = a * zc.x + b * (g / t);
    if (LAST) {
      atomicAdd(&bsum, x[node] * ynew);  // fused final dot product
    } else {
      zout[node] = make_float2(ynew, zc.y);  // carry Dinv forward
    }
  }
  if (LAST) {
    __syncthreads();
    if (threadIdx.x == 0) atomicAdd(out, bsum);
  }
}

extern "C" void kernel_launch(void* const* d_in, const int* in_sizes, int n_in,
                              void* d_out, int out_size, void* d_ws, size_t ws_size,
                              hipStream_t stream) {
  const float* x     = (const float*)d_in[0];
  const int*   nbr   = (const int*)d_in[1];
  const float* dist  = (const float*)d_in[2];
  const float* eps_p = (const float*)d_in[3];
  const float* k_p   = (const float*)d_in[4];
  const int*   nu_p  = (const int*)d_in[5];
  float* out = (float*)d_out;

  int n  = in_sizes[0];   // 1,000,000 nodes
  int ne = in_sizes[1];   // N*K = 32,000,000 edges

  float2* z0 = (float2*)d_ws;   // (y, Dinv) ping
  float2* z1 = z0 + n;          // pong          -> needs 16 MB of ws

  // d_out is poisoned before every timed launch; zero the accumulator.
  hipMemsetAsync(d_out, 0, sizeof(float), stream);

  int gridE = (ne + BLOCK - 1) / BLOCK;
  dinv_kernel<<<gridE, BLOCK, 0, stream>>>(dist, x, eps_p, z0, ne);
  sweep_kernel<false><<<gridE, BLOCK, 0, stream>>>(dist, nbr, z0, z1, x, eps_p, k_p, nu_p, out, ne);
  sweep_kernel<false><<<gridE, BLOCK, 0, stream>>>(dist, nbr, z1, z0, x, eps_p, k_p, nu_p, out, ne);
  sweep_kernel<true ><<<gridE, BLOCK, 0, stream>>>(dist, nbr, z0, z1, x, eps_p, k_p, nu_p, out, ne);
}

// Round 2
// 1153.449 us; speedup vs baseline: 2.1920x; 2.1920x over previous
//
#include <hip/hip_runtime.h>

// LaplacianKnn:  y' [i] = a*y[i] + sum_j w_e * y[nbr_e],  out = dot(x, y_nu)
//   t_e = exp(-dist_e/eps) * Dinv[nbr_e]   (row's own 1/D_i cancels)
//   w_e = b * t_e / s_i,  s_i = row-sum(t),  a = 4/eps + 2nu/k^2 + 10, b = -4/eps
// w_e is y-independent -> precompute once; sweeps gather 4B y from a 4MB
// array (fits one XCD's L2). All 128MB-class streams use non-temporal
// loads/stores so they don't evict the y gather array from L2.

static constexpr int BLOCK = 256;

__global__ __launch_bounds__(256) void dinv_kernel(
    const float* __restrict__ dist, const float* __restrict__ eps_p,
    float* __restrict__ Dinv, int n_edges) {
  int e = blockIdx.x * BLOCK + threadIdx.x;  // lane per edge, 32 lanes per row
  float inv_eps = 1.0f / eps_p[0];
  float w = 0.0f;
  if (e < n_edges) w = __expf(-__builtin_nontemporal_load(dist + e) * inv_eps);
  #pragma unroll
  for (int off = 16; off > 0; off >>= 1) w += __shfl_down(w, off, 32);
  if ((threadIdx.x & 31) == 0 && e < n_edges) Dinv[e >> 5] = 1.0f / w;
}

__global__ __launch_bounds__(256) void wcoef_kernel(
    const float* __restrict__ dist, const int* __restrict__ nbr,
    const float* __restrict__ Dinv, const float* __restrict__ eps_p,
    float* __restrict__ wout, int n_edges) {
  int e = blockIdx.x * BLOCK + threadIdx.x;
  float inv_eps = 1.0f / eps_p[0];
  float b = -4.0f * inv_eps;
  float t = 0.0f;
  if (e < n_edges) {
    int j = __builtin_nontemporal_load(nbr + e);
    t = __expf(-__builtin_nontemporal_load(dist + e) * inv_eps) * Dinv[j];
  }
  float s = t;  // butterfly so ALL lanes get the row sum
  #pragma unroll
  for (int off = 16; off > 0; off >>= 1) s += __shfl_xor(s, off, 32);
  if (e < n_edges) __builtin_nontemporal_store(b * t / s, wout + e);
}

template <bool LAST>
__global__ __launch_bounds__(256) void sweep_kernel(
    const int* __restrict__ nbr, const float* __restrict__ w,
    const float* __restrict__ yin, float* __restrict__ yout,
    const float* __restrict__ x,
    const float* __restrict__ eps_p, const float* __restrict__ k_p,
    const int* __restrict__ nu_p,
    float* __restrict__ out, int n_edges) {
  __shared__ float bsum;
  if (LAST) { if (threadIdx.x == 0) bsum = 0.0f; __syncthreads(); }
  float inv_eps = 1.0f / eps_p[0];
  float kk = k_p[0];
  float a = 4.0f * inv_eps + 2.0f * (float)nu_p[0] / (kk * kk) + 10.0f;
  int stride = gridDim.x * BLOCK;
  for (int e = blockIdx.x * BLOCK + threadIdx.x; e < n_edges; e += stride) {
    int j = __builtin_nontemporal_load(nbr + e);   // coalesced stream, bypass L2
    float g = __builtin_nontemporal_load(w + e) * yin[j];  // 4B gather, L2-resident
    #pragma unroll
    for (int off = 16; off > 0; off >>= 1) g += __shfl_down(g, off, 32);
    if ((threadIdx.x & 31) == 0) {
      int node = e >> 5;
      float ynew = a * yin[node] + g;   // w already folded b and 1/s
      if (LAST) atomicAdd(&bsum, x[node] * ynew);
      else yout[node] = ynew;
    }
  }
  if (LAST) { __syncthreads(); if (threadIdx.x == 0) atomicAdd(out, bsum); }
}

// ---- fallback (round-1 structure, used only if ws too small for w array) ----
template <bool LAST>
__global__ __launch_bounds__(256) void sweepB_kernel(
    const float* __restrict__ dist, const int* __restrict__ nbr,
    const float2* __restrict__ zin, float2* __restrict__ zout,
    const float* __restrict__ x,
    const float* __restrict__ eps_p, const float* __restrict__ k_p,
    const int* __restrict__ nu_p,
    float* __restrict__ out, int n_edges) {
  __shared__ float bsum;
  if (LAST) { if (threadIdx.x == 0) bsum = 0.0f; __syncthreads(); }
  int e = blockIdx.x * BLOCK + threadIdx.x;
  float inv_eps = 1.0f / eps_p[0];
  float t = 0.0f, g = 0.0f;
  if (e < n_edges) {
    int j = __builtin_nontemporal_load(nbr + e);
    float2 zn = zin[j];
    t = __expf(-__builtin_nontemporal_load(dist + e) * inv_eps) * zn.y;
    g = t * zn.x;
  }
  #pragma unroll
  for (int off = 16; off > 0; off >>= 1) { t += __shfl_down(t, off, 32); g += __shfl_down(g, off, 32); }
  if ((threadIdx.x & 31) == 0 && e < n_edges) {
    int node = e >> 5;
    float2 zc = zin[node];
    float kk = k_p[0];
    float a = 4.0f * inv_eps + 2.0f * (float)nu_p[0] / (kk * kk) + 10.0f;
    float b = -4.0f * inv_eps;
    float ynew = a * zc.x + b * (g / t);
    if (LAST) atomicAdd(&bsum, x[node] * ynew);
    else zout[node] = make_float2(ynew, zc.y);
  }
  if (LAST) { __syncthreads(); if (threadIdx.x == 0) atomicAdd(out, bsum); }
}

__global__ __launch_bounds__(256) void dinvB_kernel(
    const float* __restrict__ dist, const float* __restrict__ x,
    const float* __restrict__ eps_p, float2* __restrict__ z0, int n_edges) {
  int e = blockIdx.x * BLOCK + threadIdx.x;
  float inv_eps = 1.0f / eps_p[0];
  float w = 0.0f;
  if (e < n_edges) w = __expf(-__builtin_nontemporal_load(dist + e) * inv_eps);
  #pragma unroll
  for (int off = 16; off > 0; off >>= 1) w += __shfl_down(w, off, 32);
  if ((threadIdx.x & 31) == 0 && e < n_edges) {
    int node = e >> 5;
    z0[node] = make_float2(x[node], 1.0f / w);
  }
}

extern "C" void kernel_launch(void* const* d_in, const int* in_sizes, int n_in,
                              void* d_out, int out_size, void* d_ws, size_t ws_size,
                              hipStream_t stream) {
  const float* x     = (const float*)d_in[0];
  const int*   nbr   = (const int*)d_in[1];
  const float* dist  = (const float*)d_in[2];
  const float* eps_p = (const float*)d_in[3];
  const float* k_p   = (const float*)d_in[4];
  const int*   nu_p  = (const int*)d_in[5];
  float* out = (float*)d_out;

  int n  = in_sizes[0];   // 1,000,000 nodes
  int ne = in_sizes[1];   // 32,000,000 edges

  hipMemsetAsync(d_out, 0, sizeof(float), stream);
  int gridE = (ne + BLOCK - 1) / BLOCK;

  size_t needA = (size_t)ne * 4 + (size_t)n * 12;  // w + Dinv + y0 + y1
  if (ws_size >= needA) {
    float* w    = (float*)d_ws;        // [ne]
    float* Dinv = w + ne;              // [n]
    float* y0   = Dinv + n;            // [n]
    float* y1   = y0 + n;              // [n]
    dinv_kernel<<<gridE, BLOCK, 0, stream>>>(dist, eps_p, Dinv, ne);
    wcoef_kernel<<<gridE, BLOCK, 0, stream>>>(dist, nbr, Dinv, eps_p, w, ne);
    sweep_kernel<false><<<gridE, BLOCK, 0, stream>>>(nbr, w, x,  y0, x, eps_p, k_p, nu_p, out, ne);
    sweep_kernel<false><<<gridE, BLOCK, 0, stream>>>(nbr, w, y0, y1, x, eps_p, k_p, nu_p, out, ne);
    sweep_kernel<true ><<<gridE / 8, BLOCK, 0, stream>>>(nbr, w, y1, nullptr, x, eps_p, k_p, nu_p, out, ne);
  } else {
    float2* z0 = (float2*)d_ws;
    float2* z1 = z0 + n;
    dinvB_kernel<<<gridE, BLOCK, 0, stream>>>(dist, x, eps_p, z0, ne);
    sweepB_kernel<false><<<gridE, BLOCK, 0, stream>>>(dist, nbr, z0, z1, x, eps_p, k_p, nu_p, out, ne);
    sweepB_kernel<false><<<gridE, BLOCK, 0, stream>>>(dist, nbr, z1, z0, x, eps_p, k_p, nu_p, out, ne);
    sweepB_kernel<true ><<<gridE, BLOCK, 0, stream>>>(dist, nbr, z0, z1, x, eps_p, k_p, nu_p, out, ne);
  }
}